// Round 5
// baseline (195.869 us; speedup 1.0000x reference)
//
#include <hip/hip_runtime.h>
#include <math.h>

// TOF PET forward projection — Morton-sorted LOR order for gather locality.
// R3 baseline: 97 us, FETCH_SIZE 215 MB vs ~14 MB compulsory -> L2-miss bound
// (random LOR order thrashes 4 MB/XCD L2 with 8 MB image). Fix: counting-sort
// LORs by TOF-center voxel (16^3 Morton buckets, 25 mm cells) + XCD-chunked
// block swizzle so co-resident waves per XCD share a small image region.
// Also: closed-form TOF sample range [jlo,jhi] (exact per-sample test kept,
// +-2 slop -> bit-identical output) skips ~60% of sample evaluations.
// Index-path math is STRICTLY UNFUSED f32 (numpy semantics) — do not touch:
// fp contract(off), exact rn divisions, numpy op order (see R0-R3 history:
// FMA contraction => voxel flips => absmax 0.14 > 0.071 threshold).

#define LPB   4      // LORs (waves) per block
#define NBUCK 4096   // 16^3 buckets

__device__ __forceinline__ int morton4(int x, int y, int z) {
    int m = 0;
#pragma unroll
    for (int b = 0; b < 4; ++b) {
        m |= ((x >> b) & 1) << (3 * b + 0);
        m |= ((y >> b) & 1) << (3 * b + 1);
        m |= ((z >> b) & 1) << (3 * b + 2);
    }
    return m;
}

__global__ void bucket_kernel(const float* __restrict__ lors,
                              int* __restrict__ counts,
                              int* __restrict__ tmp, int n) {
    int i = blockIdx.x * 256 + threadIdx.x;
    if (i >= n) return;
    const float* lp = lors + (size_t)i * 7;
    float p1x = lp[0], p1y = lp[1], p1z = lp[2];
    float dx = lp[3] - p1x, dy = lp[4] - p1y, dz = lp[5] - p1z;
    float tt = lp[6];
    float l2 = dx * dx + dy * dy + dz * dz;
    float tc = 0.5f;
    if (l2 > 0.f) tc += tt * __frsqrt_rn(l2);       // t of TOF center
    tc = fminf(fmaxf(tc, 0.f), 1.f);
    float px = p1x + tc * dx, py = p1y + tc * dy, pz = p1z + tc * dz;
    int cx = (int)fminf(fmaxf((px + 200.f) * 0.04f, 0.f), 15.f);
    int cy = (int)fminf(fmaxf((py + 200.f) * 0.04f, 0.f), 15.f);
    int cz = (int)fminf(fmaxf((pz + 200.f) * 0.04f, 0.f), 15.f);
    int b = morton4(cx, cy, cz);
    int r = atomicAdd(&counts[b], 1);
    tmp[i] = (b << 18) | r;                          // n < 2^18
}

__global__ void scan_kernel(const int* __restrict__ counts,
                            int* __restrict__ offsets) {
    __shared__ int s[256];
    int t = threadIdx.x;
    int base = t * 16;
    int local[16];
    int sum = 0;
#pragma unroll
    for (int i = 0; i < 16; ++i) { local[i] = counts[base + i]; sum += local[i]; }
    s[t] = sum;
    __syncthreads();
    for (int off = 1; off < 256; off <<= 1) {
        int v = (t >= off) ? s[t - off] : 0;
        __syncthreads();
        s[t] += v;
        __syncthreads();
    }
    int excl = (t == 0) ? 0 : s[t - 1];
#pragma unroll
    for (int i = 0; i < 16; ++i) { offsets[base + i] = excl; excl += local[i]; }
}

__global__ void scatter_kernel(const int* __restrict__ tmp,
                               const int* __restrict__ offsets,
                               int* __restrict__ perm, int n) {
    int i = blockIdx.x * 256 + threadIdx.x;
    if (i >= n) return;
    int v = tmp[i];
    perm[offsets[v >> 18] + (v & 0x3FFFF)] = i;
}

__global__ __launch_bounds__(256) void proj_kernel(
    const float* __restrict__ image,
    const float* __restrict__ lors,
    float* __restrict__ out,
    const int* __restrict__ perm,
    int n_lors, int chunks)
{
#pragma clang fp contract(off)
    const int lane = threadIdx.x & 63;
    const int wave = threadIdx.x >> 6;
    // XCD swizzle: block i -> XCD (i&7) works the (i&7)-th eighth of sorted order
    const int sb = (blockIdx.x & 7) * chunks + (blockIdx.x >> 3);
    const int s_idx = sb * LPB + wave;
    if (s_idx >= n_lors) return;
    const int lor = perm ? perm[s_idx] : s_idx;

    const float* lp = lors + (size_t)lor * 7;
    const float p1x = lp[0], p1y = lp[1], p1z = lp[2];
    const float p2x = lp[3], p2y = lp[4], p2z = lp[5];
    const float ttof = lp[6];

    const float dx = p2x - p1x;
    const float dy = p2y - p1y;
    const float dz = p2z - p1z;

    // numpy order, unfused
    const float L = sqrtf(((dx * dx) + (dy * dy)) + (dz * dz));

    const float eps = 1e-8f;
    const float sdx = (fabsf(dx) < eps) ? eps : dx;
    const float sdy = (fabsf(dy) < eps) ? eps : dy;
    const float sdz = (fabsf(dz) < eps) ? eps : dz;

    const float tax = (-200.0f - p1x) / sdx;
    const float tbx = ( 200.0f - p1x) / sdx;
    const float tay = (-200.0f - p1y) / sdy;
    const float tby = ( 200.0f - p1y) / sdy;
    const float taz = (-200.0f - p1z) / sdz;
    const float tbz = ( 200.0f - p1z) / sdz;

    const float tmin = fmaxf(fmaxf(fmaxf(fminf(tax, tbx), fminf(tay, tby)),
                                   fminf(taz, tbz)), 0.0f);
    const float tmax = fminf(fminf(fminf(fmaxf(tax, tbx), fmaxf(tay, tby)),
                                   fmaxf(taz, tbz)), 1.0f);
    const float span = fmaxf(tmax - tmin, 0.0f);

    if (!(tmax > tmin)) {
        if (lane == 0) out[lor] = 0.0f;
        return;
    }

    // Closed-form sample range of the TOF window (monotone dev(t); +-2 slop;
    // exact per-sample test retained below -> bit-identical to full scan).
    int jlo = 0, jhi = 127;
    if (L > 0.0f) {
        const float tlo = 0.5f + (ttof - 90.0f) / L;
        const float thi = 0.5f + (ttof + 90.0f) / L;
        float jl = ((tlo - tmin) / span) * 128.0f - 0.5f;
        float jh = ((thi - tmin) / span) * 128.0f - 0.5f;
        jl = fminf(fmaxf(jl - 2.0f, 0.0f), 127.0f);
        jh = fminf(fmaxf(jh + 2.0f, -1.0f), 127.0f);
        jlo = (int)jl;
        jhi = (int)ceilf(jh);
        if (jhi > 127) jhi = 127;
    }

    float acc = 0.0f;
    for (int base = jlo; base <= jhi; base += 64) {
        const int j = base + lane;
        if (j <= jhi) {
            const float frac = ((float)j + 0.5f) / 128.0f;       // exact
            const float t = tmin + (frac * span);                 // UNFUSED
            const float dev = ((t - 0.5f) * L) - ttof;            // unfused

            if (fabsf(dev) <= 90.0f) {
                const float px = p1x + (t * dx);                  // UNFUSED
                const float py = p1y + (t * dy);
                const float pz = p1z + (t * dz);
                int vx = (int)floorf((px + 200.0f) / 3.125f);     // exact rn div
                int vy = (int)floorf((py + 200.0f) / 3.125f);
                int vz = (int)floorf((pz + 200.0f) / 3.125f);
                vx = min(max(vx, 0), 127);
                vy = min(max(vy, 0), 127);
                vz = min(max(vz, 0), 127);

                const float val = image[(((vx << 7) | vy) << 7) | vz];

                const float w = 0.06649038f *
                                __expf(((-0.5f * dev) * dev) / 900.0f);
                acc += val * w;
            }
        }
    }

#pragma unroll
    for (int off = 32; off > 0; off >>= 1)
        acc += __shfl_xor(acc, off, 64);

    if (lane == 0) {
        const float step = (span * L) / 128.0f;
        out[lor] = acc * step;
    }
}

extern "C" void kernel_launch(void* const* d_in, const int* in_sizes, int n_in,
                              void* d_out, int out_size, void* d_ws, size_t ws_size,
                              hipStream_t stream) {
    const float* image = (const float*)d_in[0];   // 128^3 fp32
    const float* lors  = (const float*)d_in[1];   // N x 7 fp32
    float* out = (float*)d_out;                   // N fp32
    const int n = in_sizes[1] / 7;

    int* counts  = (int*)d_ws;
    int* offsets = counts + NBUCK;
    int* tmp     = offsets + NBUCK;
    int* perm    = tmp + n;
    const size_t need = (size_t)(2 * NBUCK + 2 * n) * sizeof(int);
    const bool do_sort = (ws_size >= need) && (n < (1 << 18));

    const int nblocks = (n + LPB - 1) / LPB;
    const int nb8 = ((nblocks + 7) / 8) * 8;

    if (do_sort) {
        hipMemsetAsync(counts, 0, NBUCK * sizeof(int), stream);
        bucket_kernel<<<(n + 255) / 256, 256, 0, stream>>>(lors, counts, tmp, n);
        scan_kernel<<<1, 256, 0, stream>>>(counts, offsets);
        scatter_kernel<<<(n + 255) / 256, 256, 0, stream>>>(tmp, offsets, perm, n);
    }
    proj_kernel<<<nb8, 256, 0, stream>>>(image, lors, out,
                                         do_sort ? perm : (const int*)nullptr,
                                         n, nb8 >> 3);
}